// Round 4
// baseline (22.643 us; speedup 1.0000x reference)
//
#include <hip/hip_runtime.h>

constexpr int B  = 2;
constexpr int L  = 256;
constexpr int Dd = 512;
constexpr int Hh = 256;
constexpr int Oo = 16;
constexpr int BL = B * L;
constexpr int NBO = B * Oo;          // 32
constexpr int SLAB = NBO * L;        // 8192 floats per partial slot

__device__ __forceinline__ float dot4(const float4 a, const float4 b) {
    return a.x * b.x + a.y * b.y + a.z * b.z + a.w * b.w;
}
__device__ __forceinline__ float leaky(const float v) {
    return (v >= 0.f) ? v : 0.1f * v;
}

// ---------------------------------------------------------------------------
// K1: fused MLP + partial projection.
// grid = (64 rowsets of 8, 4 h-chunks of 64, 2 matrices) = 512 blocks, 256 thr.
// Phase A (GEMM): wave = 4 h-groups x 16 k-lanes, lane owns 4 W rows;
//   x-tile (8 rows, 16 KB) in LDS; shfl_xor(1/2/4/8) k-reduction.
//   h = leaky(acc + b) kept in LDS only — never written to global.
// Phase B (projection partials over this block's 64-h slice):
//   thread (r,o) in t<128:  s1 = Wf1.h, s2 = Wf2.h, s3 = Wf3.h (m=0 only)
//   m=0: PA[hc]=s1, PB[hc]=0.5*s2, PD[hc]=s3
//   m=1: PA[4+hc]=0.5*s2, PB[4+hc]=-s1
// ---------------------------------------------------------------------------
__global__ __launch_bounds__(256) void mlp_proj_kernel(
    const float* __restrict__ x,
    const float* __restrict__ W1, const float* __restrict__ b1,
    const float* __restrict__ W2, const float* __restrict__ b2,
    const float* __restrict__ Wf,
    float* __restrict__ PA, float* __restrict__ PB, float* __restrict__ PD)
{
    const int rs = blockIdx.x;   // rowset: 8 bl-rows
    const int hc = blockIdx.y;   // h-chunk: 64 h
    const int m  = blockIdx.z;
    const float* __restrict__ W  = m ? W2 : W1;
    const float* __restrict__ bb = m ? b2 : b1;

    __shared__ float xs[8 * Dd];       // 16 KB
    __shared__ float hbuf[8][64];      // 2 KB
    const int t = threadIdx.x;
    {
        const float4* xg = reinterpret_cast<const float4*>(x + (size_t)rs * 8 * Dd);
        float4* s4 = reinterpret_cast<float4*>(xs);
        #pragma unroll
        for (int i = 0; i < 4; ++i) s4[t + 256 * i] = xg[t + 256 * i];
    }
    __syncthreads();

    const int wave = t >> 6, lane = t & 63, g = lane >> 4, kl = lane & 15;
    const int h0 = hc * 64 + wave * 16 + g * 4;   // global h of first owned row

    const float4* w0 = reinterpret_cast<const float4*>(W + (size_t)(h0 + 0) * Dd);
    const float4* w1 = reinterpret_cast<const float4*>(W + (size_t)(h0 + 1) * Dd);
    const float4* w2 = reinterpret_cast<const float4*>(W + (size_t)(h0 + 2) * Dd);
    const float4* w3 = reinterpret_cast<const float4*>(W + (size_t)(h0 + 3) * Dd);
    const float4* xs4 = reinterpret_cast<const float4*>(xs);

    float acc[8][4];
    #pragma unroll
    for (int r = 0; r < 8; ++r)
        #pragma unroll
        for (int j = 0; j < 4; ++j) acc[r][j] = 0.f;

    #pragma unroll
    for (int s = 0; s < 8; ++s) {
        const int ko = s * 16 + kl;
        const float4 a = w0[ko], b_ = w1[ko], c = w2[ko], d = w3[ko];
        #pragma unroll
        for (int r = 0; r < 8; ++r) {
            const float4 xv = xs4[r * 128 + ko];
            acc[r][0] += dot4(xv, a);
            acc[r][1] += dot4(xv, b_);
            acc[r][2] += dot4(xv, c);
            acc[r][3] += dot4(xv, d);
        }
    }

    #pragma unroll
    for (int r = 0; r < 8; ++r)
        #pragma unroll
        for (int j = 0; j < 4; ++j) {
            float v = acc[r][j];
            v += __shfl_xor(v, 1); v += __shfl_xor(v, 2);
            v += __shfl_xor(v, 4); v += __shfl_xor(v, 8);
            acc[r][j] = v;
        }

    if (kl == 0) {
        const float4 bv = *reinterpret_cast<const float4*>(bb + h0);
        const int hl = wave * 16 + g * 4;   // block-local h
        #pragma unroll
        for (int r = 0; r < 8; ++r) {
            float4 o;
            o.x = leaky(acc[r][0] + bv.x);
            o.y = leaky(acc[r][1] + bv.y);
            o.z = leaky(acc[r][2] + bv.z);
            o.w = leaky(acc[r][3] + bv.w);
            *reinterpret_cast<float4*>(&hbuf[r][hl]) = o;
        }
    }
    __syncthreads();

    // Phase B: partial projections over the 64-h slice.
    if (t < 128) {
        const int r = t >> 4, o = t & 15;
        const float4* wf1 = reinterpret_cast<const float4*>(Wf + (size_t)o * (3 * Hh) + hc * 64);
        const float4* wf2 = reinterpret_cast<const float4*>(Wf + (size_t)o * (3 * Hh) + Hh + hc * 64);
        const float4* wf3 = reinterpret_cast<const float4*>(Wf + (size_t)o * (3 * Hh) + 2 * Hh + hc * 64);
        const float4* hv  = reinterpret_cast<const float4*>(&hbuf[r][0]);

        float s1 = 0.f, s2 = 0.f, s3 = 0.f;
        #pragma unroll
        for (int k = 0; k < 16; ++k) {
            const float4 h4 = hv[k];
            s1 += dot4(wf1[k], h4);
            s2 += dot4(wf2[k], h4);
            if (m == 0) s3 += dot4(wf3[k], h4);
        }

        const int bl = rs * 8 + r;
        const int b = bl >> 8, l = bl & 255;
        const size_t idx = ((size_t)(b * Oo + o)) * L + l;
        if (m == 0) {
            PA[(size_t)hc * SLAB + idx] = s1;
            PB[(size_t)hc * SLAB + idx] = 0.5f * s2;
            PD[(size_t)hc * SLAB + idx] = s3;
        } else {
            PA[(size_t)(4 + hc) * SLAB + idx] = 0.5f * s2;
            PB[(size_t)(4 + hc) * SLAB + idx] = -s1;
        }
    }
}

// ---------------------------------------------------------------------------
// K2: partial-reduce + cumsum + epilogue. grid = 32 bo x 16 i-chunks = 512.
// Reduce 8 PA/PB slots and 4 PD slots (coalesced over l = t), scan D in LDS
// (Hillis-Steele), then write the 16 x 256 tile:
//   out[bo,i,j] = A[j] + Bv[i] + bf[o] + (C[j]-C[i-1])/(j-i+1+1e-9)
// i = j+1 numerator is exactly 0 (identical LDS values) -> no 1e9 blowup.
// ---------------------------------------------------------------------------
__global__ __launch_bounds__(256) void out_kernel(
    const float* __restrict__ PA, const float* __restrict__ PB,
    const float* __restrict__ PD, const float* __restrict__ bf,
    float* __restrict__ out)
{
    const int bo = blockIdx.x >> 4;    // 0..31
    const int ig = blockIdx.x & 15;    // i-chunk of 16
    const int t  = threadIdx.x;

    __shared__ float Asm[L], Bsm[L], ca[L], cb[L];
    {
        float a = 0.f, bsum = 0.f, d = 0.f;
        #pragma unroll
        for (int s = 0; s < 8; ++s) {
            a    += PA[(size_t)s * SLAB + (size_t)bo * L + t];
            bsum += PB[(size_t)s * SLAB + (size_t)bo * L + t];
        }
        #pragma unroll
        for (int s = 0; s < 4; ++s)
            d += PD[(size_t)s * SLAB + (size_t)bo * L + t];
        Asm[t] = a; Bsm[t] = bsum; ca[t] = d;
    }
    __syncthreads();

    float* src = ca;
    float* dst = cb;
    #pragma unroll
    for (int off = 1; off < L; off <<= 1) {
        const float s = src[t] + ((t >= off) ? src[t - off] : 0.f);
        dst[t] = s;
        __syncthreads();
        float* tmp = src; src = dst; dst = tmp;
    }
    // src[l] = inclusive prefix C[l]

    const float bfv = bf[bo & (Oo - 1)];
    const int j0 = (t & 63) * 4;
    const int is = t >> 6;

    const float4 Av = *reinterpret_cast<const float4*>(Asm + j0);
    const float4 Cv = *reinterpret_cast<const float4*>(src + j0);

    #pragma unroll
    for (int ii = 0; ii < 4; ++ii) {
        const int i = ig * 16 + is * 4 + ii;
        const float cp   = (i > 0) ? src[i - 1] : 0.f;
        const float base = Bsm[i] + bfv;
        float4 r;
        r.x = Av.x + base + (Cv.x - cp) / ((float)(j0 + 0 - i + 1) + 1e-9f);
        r.y = Av.y + base + (Cv.y - cp) / ((float)(j0 + 1 - i + 1) + 1e-9f);
        r.z = Av.z + base + (Cv.z - cp) / ((float)(j0 + 2 - i + 1) + 1e-9f);
        r.w = Av.w + base + (Cv.w - cp) / ((float)(j0 + 3 - i + 1) + 1e-9f);
        *reinterpret_cast<float4*>(out + ((size_t)bo * L + i) * L + j0) = r;
    }
}

// ---------------------------------------------------------------------------
extern "C" void kernel_launch(void* const* d_in, const int* in_sizes, int n_in,
                              void* d_out, int out_size, void* d_ws, size_t ws_size,
                              hipStream_t stream)
{
    const float* x  = (const float*)d_in[0];
    const float* W1 = (const float*)d_in[1];
    const float* b1 = (const float*)d_in[2];
    const float* W2 = (const float*)d_in[3];
    const float* b2 = (const float*)d_in[4];
    const float* Wf = (const float*)d_in[5];
    const float* bf = (const float*)d_in[6];
    float* out = (float*)d_out;

    float* ws = (float*)d_ws;
    float* PA = ws;                       // 8 * 8192
    float* PB = PA + 8 * (size_t)SLAB;    // 8 * 8192
    float* PD = PB + 8 * (size_t)SLAB;    // 4 * 8192

    hipLaunchKernelGGL(mlp_proj_kernel, dim3(BL / 8, 4, 2), dim3(256), 0, stream,
                       x, W1, b1, W2, b2, Wf, PA, PB, PD);
    hipLaunchKernelGGL(out_kernel, dim3(NBO * 16), dim3(256), 0, stream,
                       PA, PB, PD, bf, out);
}